// Round 5
// baseline (340.431 us; speedup 1.0000x reference)
//
#include <hip/hip_runtime.h>

#define B_ROWS 4096
#define K_Q    32768
#define D_DIM  256
#define C_CLS  100

typedef unsigned short u16;
typedef __attribute__((ext_vector_type(8))) short short8_t;   // 8 bf16 (4 VGPR)
typedef __attribute__((ext_vector_type(4))) float f32x4;

__device__ inline u16 f2bf(float x) {   // RNE float->bf16
  unsigned int u = __float_as_uint(x);
  u = (u + 0x7FFFu + ((u >> 16) & 1u)) >> 16;
  return (u16)u;
}

__device__ inline float fast_sqrt(float x) {    // single v_sqrt_f32
  return __builtin_amdgcn_sqrtf(x);
}

// ---------- K1: fused per-class histogram + fp32->bf16 cast of Q ----------
// grid (128 kc x 4 dc), 256 threads; 256 queue rows per block.
__global__ void k_histcast(const float* __restrict__ q, const int* __restrict__ lab,
                           int* __restrict__ counts, float* __restrict__ sums,
                           u16* __restrict__ qbf) {
  const int kc = blockIdx.x;          // 128 chunks of 256 queue rows
  const int dc = blockIdx.y;          // 4 chunks of 64 cols
  __shared__ float lsum[C_CLS * 64];
  __shared__ int lcnt[C_CLS];
  const int tid = threadIdx.x;
  for (int i = tid; i < C_CLS * 64; i += 256) lsum[i] = 0.f;
  if (dc == 0 && tid < C_CLS) lcnt[tid] = 0;
  __syncthreads();

  const int rloc = tid >> 4;          // 16 rows per iteration
  const int c4 = tid & 15;            // float4 slot within 64 cols
  for (int it = 0; it < 16; ++it) {
    const int k = kc * 256 + it * 16 + rloc;
    const int c = lab[k];
    const size_t off = (size_t)k * D_DIM + dc * 64 + c4 * 4;
    float4 v = *(const float4*)(q + off);
    ushort4 o;
    o.x = f2bf(v.x); o.y = f2bf(v.y); o.z = f2bf(v.z); o.w = f2bf(v.w);
    *(ushort4*)(qbf + off) = o;
    const int base = c * 64 + c4 * 4;
    atomicAdd(&lsum[base + 0], v.x);
    atomicAdd(&lsum[base + 1], v.y);
    atomicAdd(&lsum[base + 2], v.z);
    atomicAdd(&lsum[base + 3], v.w);
    if (dc == 0 && c4 == 0) atomicAdd(&lcnt[c], 1);
  }
  __syncthreads();
  for (int i = tid; i < C_CLS * 64; i += 256) {
    int c = i >> 6, d = i & 63;
    atomicAdd(&sums[c * D_DIM + dc * 64 + d], lsum[i]);
  }
  if (dc == 0 && tid < C_CLS) atomicAdd(&counts[tid], lcnt[tid]);
}

// ---------- K2: centroid normalize ----------
__global__ void k_cnorm(const int* __restrict__ counts, const float* __restrict__ sums,
                        float* __restrict__ cnorm) {
  __shared__ float red[4];
  const int c = blockIdx.x, d = threadIdx.x;
  float cnt = (float)counts[c];
  float v = sums[c * D_DIM + d] / cnt;
  float ss = v * v;
  #pragma unroll
  for (int o = 1; o < 64; o <<= 1) ss += __shfl_xor(ss, o);
  if ((d & 63) == 0) red[d >> 6] = ss;
  __syncthreads();
  float norm = sqrtf(red[0] + red[1] + red[2] + red[3]);
  cnorm[c * D_DIM + d] = v / fmaxf(norm, 1e-12f);
}

// ---------- K3: pseudo-labels (fp32 argmax) + fused A bf16 cast ----------
// 16 rows/block of 16 lanes each; 256 blocks.
__global__ void k_pseudo(const float* __restrict__ bf, const float* __restrict__ cn,
                         int* __restrict__ pseudo, u16* __restrict__ abf) {
  const int tid = threadIdx.x;
  const int rloc = tid >> 4;                    // 16 rows/block
  const int sub = tid & 15;                     // 16 lanes/row
  const int row = blockIdx.x * 16 + rloc;
  float4 a[4];
  const float4* ap = (const float4*)(bf + (size_t)row * D_DIM);
  #pragma unroll
  for (int j = 0; j < 4; ++j) a[j] = ap[sub + j * 16];
  #pragma unroll
  for (int j = 0; j < 4; ++j) {
    ushort4 o;
    o.x = f2bf(a[j].x); o.y = f2bf(a[j].y); o.z = f2bf(a[j].z); o.w = f2bf(a[j].w);
    *(ushort4*)(abf + (size_t)row * D_DIM + (sub + j * 16) * 4) = o;
  }
  float best = -1e30f; int bi = 0;
  for (int c = 0; c < C_CLS; ++c) {
    const float4* cp = (const float4*)(cn + c * D_DIM);
    float s = 0.f;
    #pragma unroll
    for (int j = 0; j < 4; ++j) {
      float4 b = cp[sub + j * 16];
      s += a[j].x * b.x + a[j].y * b.y + a[j].z * b.z + a[j].w * b.w;
    }
    s += __shfl_xor(s, 1); s += __shfl_xor(s, 2);
    s += __shfl_xor(s, 4); s += __shfl_xor(s, 8);
    if (s > best) { best = s; bi = c; }         // strict > = first index (jnp.argmax)
  }
  if (sub == 0) pseudo[row] = bi;
}

// ---------- K5: fused bf16 MFMA GEMM + sqrt + masked row-sums (no LDS) ----------
// 1024 blocks x 256 thr (4 waves, 2wr x 2wc). Wave = 32 rows x 32 cols per step.
// Block = 64 rows x 2048-col slice, 32 steps of 64 cols. A-frags in regs (64 VGPR),
// B streamed per-lane from L1/L2, no barriers; waves drift for cross-wave
// MFMA/VALU/VMEM overlap. __launch_bounds__(256,4): VGPR<=128 -> 4 blocks/CU.
__global__ __launch_bounds__(256, 4) void k_main(
    const u16* __restrict__ Abf, const u16* __restrict__ Qbf,
    const int* __restrict__ lab, const int* __restrict__ pseudo,
    float* __restrict__ S_all, float* __restrict__ S_match) {
  // XCD-bijective swizzle: xcd = bid&7 -> o-chunk of 128 blocks = 2 col-slices
  // (4MB Q bf16) x 64 row-blocks, concurrently resident per XCD.
  const int bid = blockIdx.x;
  const int o = (bid & 7) * 128 + (bid >> 3);
  const int cs = o >> 6;              // 0..15 col slice (2048 cols)
  const int rb = o & 63;              // 0..63 row block (64 rows)

  const int tid = threadIdx.x;
  const int w = tid >> 6;
  const int wr = w >> 1, wc = w & 1;
  const int l = tid & 63;
  const int q16 = l & 15, hi = l >> 4;
  const int rowA = rb * 64 + wr * 32;           // wave's 32 rows
  const int colW = cs * 2048 + wc * 32;         // wave's col base within slice

  // A-fragments: 2(m) x 8(kt) short8 = 64 VGPR, loaded once
  short8_t areg[2][8];
  #pragma unroll
  for (int m = 0; m < 2; ++m)
    #pragma unroll
    for (int kt = 0; kt < 8; ++kt)
      areg[m][kt] = *(const short8_t*)(Abf + (size_t)(rowA + m * 16 + q16) * D_DIM + kt * 32 + hi * 8);

  int pse[2][4];
  #pragma unroll
  for (int m = 0; m < 2; ++m)
    #pragma unroll
    for (int j = 0; j < 4; ++j)
      pse[m][j] = pseudo[rowA + m * 16 + hi * 4 + j];

  float pa[2][4], pm_[2][4];
  #pragma unroll
  for (int m = 0; m < 2; ++m)
    #pragma unroll
    for (int j = 0; j < 4; ++j) { pa[m][j] = 0.f; pm_[m][j] = 0.f; }

  const u16* bbase = Qbf + (size_t)(colW + q16) * D_DIM + hi * 8;
  const int* lbase = lab + colW + q16;

  #pragma unroll 1
  for (int cb = 0; cb < 32; ++cb) {
    const int lbl0 = lbase[cb * 64];            // issue early: hidden under MFMAs
    const int lbl1 = lbase[cb * 64 + 16];

    f32x4 acc[2][2];
    #pragma unroll
    for (int m = 0; m < 2; ++m)
      #pragma unroll
      for (int n = 0; n < 2; ++n)
        #pragma unroll
        for (int j = 0; j < 4; ++j) acc[m][n][j] = 0.f;

    const u16* bp = bbase + (size_t)(cb * 64) * D_DIM;
    #pragma unroll
    for (int kt = 0; kt < 8; ++kt) {
      short8_t b0 = *(const short8_t*)(bp + kt * 32);
      short8_t b1 = *(const short8_t*)(bp + 16 * D_DIM + kt * 32);
      acc[0][0] = __builtin_amdgcn_mfma_f32_16x16x32_bf16(areg[0][kt], b0, acc[0][0], 0, 0, 0);
      acc[1][0] = __builtin_amdgcn_mfma_f32_16x16x32_bf16(areg[1][kt], b0, acc[1][0], 0, 0, 0);
      acc[0][1] = __builtin_amdgcn_mfma_f32_16x16x32_bf16(areg[0][kt], b1, acc[0][1], 0, 0, 0);
      acc[1][1] = __builtin_amdgcn_mfma_f32_16x16x32_bf16(areg[1][kt], b1, acc[1][1], 0, 0, 0);
    }

    // MAE epilogue (registers only; fast_sqrt = single v_sqrt_f32)
    #pragma unroll
    for (int m = 0; m < 2; ++m)
      #pragma unroll
      for (int j = 0; j < 4; ++j) {
        const int p = pse[m][j];
        float mae0 = fast_sqrt(fmaxf(__builtin_fmaf(-2.0f, acc[m][0][j], 2.000001f), 0.0f));
        float mae1 = fast_sqrt(fmaxf(__builtin_fmaf(-2.0f, acc[m][1][j], 2.000001f), 0.0f));
        pa[m][j] += mae0 + mae1;
        pm_[m][j] += (lbl0 == p ? mae0 : 0.0f) + (lbl1 == p ? mae1 : 0.0f);
      }
  }

  // once per block: reduce over 16 q-lanes, then atomics
  #pragma unroll
  for (int m = 0; m < 2; ++m)
    #pragma unroll
    for (int j = 0; j < 4; ++j) {
      float va = pa[m][j], vm = pm_[m][j];
      va += __shfl_xor(va, 1); va += __shfl_xor(va, 2);
      va += __shfl_xor(va, 4); va += __shfl_xor(va, 8);
      vm += __shfl_xor(vm, 1); vm += __shfl_xor(vm, 2);
      vm += __shfl_xor(vm, 4); vm += __shfl_xor(vm, 8);
      if (q16 == 0) {
        const int gr = rowA + m * 16 + hi * 4 + j;
        atomicAdd(&S_all[gr], va);
        atomicAdd(&S_match[gr], vm);
      }
    }
}

// ---------- K6: final scalar ----------
__global__ void k_final(const float* __restrict__ S_all, const float* __restrict__ S_match,
                        const int* __restrict__ pseudo, const int* __restrict__ counts,
                        float* __restrict__ out) {
  __shared__ float r1[16], r2[16];
  const int tid = threadIdx.x;
  float s1 = 0.f, s2 = 0.f;
  for (int b = tid; b < B_ROWS; b += 1024) {
    float cnt = (float)counts[pseudo[b]];
    float sm = S_match[b], sa = S_all[b];
    s1 += sm / (cnt + 1e-6f);
    s2 += (sa - sm) / ((float)K_Q - cnt + 1e-6f);
  }
  #pragma unroll
  for (int o = 1; o < 64; o <<= 1) { s1 += __shfl_xor(s1, o); s2 += __shfl_xor(s2, o); }
  if ((tid & 63) == 0) { r1[tid >> 6] = s1; r2[tid >> 6] = s2; }
  __syncthreads();
  if (tid == 0) {
    float t1 = 0.f, t2 = 0.f;
    #pragma unroll
    for (int i = 0; i < 16; ++i) { t1 += r1[i]; t2 += r2[i]; }
    out[0] = t1 / (float)B_ROWS + 2.0f - t2 / (float)B_ROWS;
  }
}

extern "C" void kernel_launch(void* const* d_in, const int* in_sizes, int n_in,
                              void* d_out, int out_size, void* d_ws, size_t ws_size,
                              hipStream_t stream) {
  const float* batch = (const float*)d_in[0];
  const float* queue = (const float*)d_in[1];
  const int*   lab   = (const int*)d_in[2];

  char* ws = (char*)d_ws;
  int*   counts  = (int*)  (ws + 0);
  float* sums    = (float*)(ws + 512);
  float* S_all   = (float*)(ws + 102912);
  float* S_match = (float*)(ws + 119296);
  float* cnorm   = (float*)(ws + 135680);
  int*   pseudo  = (int*)  (ws + 238080);
  u16*   Abf     = (u16*)  (ws + 254464);
  u16*   Qbf     = (u16*)  (ws + 254464 + 2097152);

  (void)hipMemsetAsync(d_ws, 0, 135680, stream);  // counts+sums+S_all+S_match

  k_histcast<<<dim3(128, 4), 256, 0, stream>>>(queue, lab, counts, sums, Qbf);
  k_cnorm   <<<C_CLS, 256, 0, stream>>>(counts, sums, cnorm);
  k_pseudo  <<<B_ROWS / 16, 256, 0, stream>>>(batch, cnorm, pseudo, Abf);
  k_main    <<<1024, 256, 0, stream>>>(Abf, Qbf, lab, pseudo, S_all, S_match);
  k_final   <<<1, 1024, 0, stream>>>(S_all, S_match, pseudo, counts, (float*)d_out);
}